// Round 1
// baseline (986.482 us; speedup 1.0000x reference)
//
#include <hip/hip_runtime.h>
#include <hip/hip_bf16.h>

// Problem constants
#define NTOK 32768
#define DIM  256
#define KCB  4096

// Tiling
#define BM 128            // rows (tokens) per block; block owns full K
#define BN 256            // codes per col-tile
#define BK 64             // D-chunk per MFMA staging step
#define NTILE (KCB / BN)  // 16
#define NCHUNK (DIM / BK) // 4
#define NTHREADS 512      // 8 waves
#define CAND_CAP 32
#define MARGIN 4.0f       // >= 2x worst-case bf16 dist error

typedef __attribute__((ext_vector_type(8))) short s8v;   // 8 bf16 in 4 VGPRs
typedef __attribute__((ext_vector_type(4))) float f32x4;

// fp32 -> bf16 round-to-nearest-even (finite inputs)
__device__ __forceinline__ unsigned short f2bf(float f) {
    union { float f; unsigned u; } v; v.f = f;
    unsigned r = v.u + 0x7FFFu + ((v.u >> 16) & 1u);
    return (unsigned short)(r >> 16);
}

// LDS swizzles: XOR bit4 of byte-in-row with (row&7) -> conflict-free b128 reads
__device__ __forceinline__ int swzX(int row, int b) {   // xs rows: 512 B (256 bf16)
    return row * 512 + (b ^ ((row & 7) << 4));
}
__device__ __forceinline__ int swzE(int row, int b) {   // es rows: 128 B (64 bf16)
    return row * 128 + (b ^ ((row & 7) << 4));
}

__global__ __launch_bounds__(NTHREADS, 2)
void vq_main(const float* __restrict__ x, const float* __restrict__ e,
             float* __restrict__ outq, float* __restrict__ outi,
             float* __restrict__ outd)
{
    __shared__ short xs[BM * DIM];          // 64 KB, swizzled bf16, full x strip
    __shared__ short es[BN * BK];           // 32 KB, swizzled bf16, e chunk
    __shared__ float xsq[BM];
    __shared__ float esq[BN];
    __shared__ unsigned minb[BM];           // running min (float bits, dist>=0)
    __shared__ int cnt[BM];
    __shared__ int cand[BM * CAND_CAP];     // 16 KB candidate indices

    const int tid = threadIdx.x;
    const int w   = tid >> 6;    // wave 0..7
    const int l   = tid & 63;    // lane
    const int g   = l >> 4;      // k-group 0..3
    const int lr  = l & 15;      // lane-in-group
    const int brow = blockIdx.x * BM;

    // ---- init bookkeeping ----
    for (int i = tid; i < BM; i += NTHREADS) { minb[i] = 0x7F800000u; cnt[i] = 0; }
    for (int i = tid; i < BN; i += NTHREADS) esq[i] = 0.0f;

    // ---- stage full x strip to LDS (bf16, swizzled) + per-row x_sq ----
    // wave w, iter k handles row w + 8k; 64 lanes * float4 = full 256-elem row
    const float4* xf4 = (const float4*)x;
    for (int k = 0; k < BM / 8; ++k) {
        int row = w + 8 * k;
        float4 v = xf4[(brow + row) * (DIM / 4) + l];
        unsigned lo = (unsigned)f2bf(v.x) | ((unsigned)f2bf(v.y) << 16);
        unsigned hi = (unsigned)f2bf(v.z) | ((unsigned)f2bf(v.w) << 16);
        uint2 p; p.x = lo; p.y = hi;
        *(uint2*)((char*)xs + swzX(row, l * 8)) = p;
        float s = v.x*v.x + v.y*v.y + v.z*v.z + v.w*v.w;
        #pragma unroll
        for (int m = 32; m >= 1; m >>= 1) s += __shfl_xor(s, m);
        if (l == 0) xsq[row] = s;
    }
    __syncthreads();

    const int wr = w >> 2;          // 0..1 : row half
    const int wc = w & 3;           // 0..3 : col quarter
    const int rowb = wr * 64;
    const int colb = wc * 64;
    const float4* ef4 = (const float4*)e;

    for (int ct = 0; ct < NTILE; ++ct) {
        f32x4 acc[4][4];
        #pragma unroll
        for (int fi = 0; fi < 4; ++fi)
            #pragma unroll
            for (int fj = 0; fj < 4; ++fj)
                acc[fi][fj] = (f32x4){0.f, 0.f, 0.f, 0.f};

        for (int ch = 0; ch < NCHUNK; ++ch) {
            // ---- stage e chunk [256 codes x 64 d] fp32->bf16 + e_sq partial ----
            #pragma unroll
            for (int k = 0; k < 8; ++k) {
                int idx = tid + NTHREADS * k;     // 0..4095
                int row = idx >> 4;               // code in tile (16 lanes/row)
                int c4  = idx & 15;
                float4 v = ef4[(ct * BN + row) * (DIM / 4) + ch * 16 + c4];
                unsigned lo = (unsigned)f2bf(v.x) | ((unsigned)f2bf(v.y) << 16);
                unsigned hi = (unsigned)f2bf(v.z) | ((unsigned)f2bf(v.w) << 16);
                uint2 p; p.x = lo; p.y = hi;
                *(uint2*)((char*)es + swzE(row, c4 * 8)) = p;
                float s = v.x*v.x + v.y*v.y + v.z*v.z + v.w*v.w;
                s += __shfl_xor(s, 1); s += __shfl_xor(s, 2);
                s += __shfl_xor(s, 4); s += __shfl_xor(s, 8);
                if (lr == 0) atomicAdd(&esq[row], s);
            }
            __syncthreads();

            // ---- MFMA: 2 k-steps of 32 within the 64-wide chunk ----
            #pragma unroll
            for (int s = 0; s < 2; ++s) {
                s8v a[4], b[4];
                #pragma unroll
                for (int fi = 0; fi < 4; ++fi) {
                    int row = rowb + fi * 16 + lr;            // A: row = lane&15
                    a[fi] = *(const s8v*)((const char*)xs +
                            swzX(row, ch * 128 + s * 64 + g * 16));
                }
                #pragma unroll
                for (int fj = 0; fj < 4; ++fj) {
                    int row = colb + fj * 16 + lr;            // B: col = lane&15
                    b[fj] = *(const s8v*)((const char*)es +
                            swzE(row, s * 64 + g * 16));
                }
                #pragma unroll
                for (int fi = 0; fi < 4; ++fi)
                    #pragma unroll
                    for (int fj = 0; fj < 4; ++fj)
                        acc[fi][fj] = __builtin_amdgcn_mfma_f32_16x16x32_bf16(
                            a[fi], b[fj], acc[fi][fj], 0, 0, 0);
            }
            __syncthreads();
        }

        // ---- epilogue: dist = xsq + esq - 2*dot, clamp, store, row-min ----
        #pragma unroll
        for (int fi = 0; fi < 4; ++fi) {
            #pragma unroll
            for (int rg = 0; rg < 4; ++rg) {
                int r = rowb + fi * 16 + g * 4 + rg;          // C/D: row=(l>>4)*4+reg
                float xq = xsq[r];
                float m = 1e30f;
                #pragma unroll
                for (int fj = 0; fj < 4; ++fj) {
                    int c = colb + fj * 16 + lr;              // C/D: col=lane&15
                    float d = xq + esq[c] - 2.0f * acc[fi][fj][rg];
                    d = fmaxf(d, 0.0f);
                    acc[fi][fj][rg] = d;
                    outd[(brow + r) * KCB + ct * BN + c] = d;
                    m = fminf(m, d);
                }
                m = fminf(m, __shfl_xor(m, 1));
                m = fminf(m, __shfl_xor(m, 2));
                m = fminf(m, __shfl_xor(m, 4));
                m = fminf(m, __shfl_xor(m, 8));
                if (lr == 0) atomicMin(&minb[r], __float_as_uint(m));
            }
        }
        __syncthreads();

        // ---- candidate append vs final running min; re-zero esq for next tile ----
        #pragma unroll
        for (int fi = 0; fi < 4; ++fi) {
            #pragma unroll
            for (int rg = 0; rg < 4; ++rg) {
                int r = rowb + fi * 16 + g * 4 + rg;
                float thr = __uint_as_float(minb[r]) + MARGIN;
                #pragma unroll
                for (int fj = 0; fj < 4; ++fj) {
                    if (acc[fi][fj][rg] <= thr) {
                        int pos = atomicAdd(&cnt[r], 1);
                        if (pos < CAND_CAP)
                            cand[r * CAND_CAP + pos] = ct * BN + colb + fj * 16 + lr;
                    }
                }
            }
        }
        for (int i = tid; i < BN; i += NTHREADS) esq[i] = 0.0f;
        __syncthreads();
    }

    // ---- refinement: exact fp64 distance over candidates; outputs ----
    float4* qf4 = (float4*)outq;
    for (int r = w; r < BM; r += 8) {
        int grow = brow + r;
        int nc = min(cnt[r], CAND_CAP);
        double best = 1e300;
        int bestj = 0x7FFFFFFF;
        float4 xv = xf4[grow * (DIM / 4) + l];
        for (int c = 0; c < nc; ++c) {
            int j = cand[r * CAND_CAP + c];
            float4 ev = ef4[j * (DIM / 4) + l];
            double dx = (double)xv.x - (double)ev.x; double s = dx * dx;
            double dy = (double)xv.y - (double)ev.y; s += dy * dy;
            double dz = (double)xv.z - (double)ev.z; s += dz * dz;
            double dw = (double)xv.w - (double)ev.w; s += dw * dw;
            #pragma unroll
            for (int m = 32; m >= 1; m >>= 1) s += __shfl_xor(s, m);
            if (s < best || (s == best && j < bestj)) { best = s; bestj = j; }
        }
        if (l == 0) outi[grow] = (float)bestj;
        float4 q = ef4[bestj * (DIM / 4) + l];
        qf4[grow * (DIM / 4) + l] = q;
    }
}

extern "C" void kernel_launch(void* const* d_in, const int* in_sizes, int n_in,
                              void* d_out, int out_size, void* d_ws, size_t ws_size,
                              hipStream_t stream) {
    const float* x = (const float*)d_in[0];      // [32768, 256] f32
    const float* e = (const float*)d_in[1];      // [1, 4096, 256] f32
    float* outq = (float*)d_out;                 // quantize [32768*256]
    float* outi = outq + (size_t)NTOK * DIM;     // embed_ind as float [32768]
    float* outd = outi + NTOK;                   // dist [32768*4096]
    vq_main<<<dim3(NTOK / BM), dim3(NTHREADS), 0, stream>>>(x, e, outq, outi, outd);
}

// Round 2
// 875.961 us; speedup vs baseline: 1.1262x; 1.1262x over previous
//
#include <hip/hip_runtime.h>

#define NTOK 32768
#define DIM  256
#define KCB  4096
#define MARGIN 4.0f
#define CAP  24

typedef __attribute__((ext_vector_type(8))) short s8v;   // 8 bf16
typedef __attribute__((ext_vector_type(4))) float f32x4;

__device__ __forceinline__ unsigned short f2bf(float f) {
    union { float f; unsigned u; } v; v.f = f;
    unsigned r = v.u + 0x7FFFu + ((v.u >> 16) & 1u);
    return (unsigned short)(r >> 16);
}

// ---------------------------------------------------------------------------
// prep: fragment-order bf16 copies of e and x, plus exact fp32 sq-norms.
// Element (row, d): rb=row>>4, lr=row&15, ks=d>>5, g=(d>>3)&3, m=d&7
//   frag elem index = rb*4096 + ks*512 + (g*16+lr)*8 + m
// One wave per row; lane l holds d = 4l..4l+3.
// ---------------------------------------------------------------------------
__global__ __launch_bounds__(64)
void prep(const float* __restrict__ x, const float* __restrict__ e,
          unsigned short* __restrict__ eb, unsigned short* __restrict__ xb,
          float* __restrict__ esq, float* __restrict__ xsq)
{
    int j = blockIdx.x;
    int l = threadIdx.x;
    const float4* src; unsigned short* dstb; float* dsts; int row;
    if (j < KCB) { src = (const float4*)e; dstb = eb; dsts = esq; row = j; }
    else         { src = (const float4*)x; dstb = xb; dsts = xsq; row = j - KCB; }

    float4 v = src[(size_t)row * 64 + l];
    float s = v.x*v.x + v.y*v.y + v.z*v.z + v.w*v.w;
    #pragma unroll
    for (int m = 32; m >= 1; m >>= 1) s += __shfl_xor(s, m);
    if (l == 0) dsts[row] = s;

    int rb = row >> 4, lr = row & 15;
    int ks = l >> 3, g = (l >> 1) & 3;
    unsigned lo = (unsigned)f2bf(v.x) | ((unsigned)f2bf(v.y) << 16);
    unsigned hi = (unsigned)f2bf(v.z) | ((unsigned)f2bf(v.w) << 16);
    uint2 p; p.x = lo; p.y = hi;
    size_t eidx = (size_t)rb * 4096 + ks * 512 + (g * 16 + lr) * 8 + (l & 1) * 4;
    *(uint2*)(dstb + eidx) = p;
}

// ---------------------------------------------------------------------------
// main: 1024 waves, each owns 32 rows x full K. No barriers in hot loop.
// A in 64 VGPRs; B streamed from L2 with 4-slot ring (3 k-steps of prefetch);
// double-buffered acc so epilogue overlaps next col-block's MFMAs.
// ---------------------------------------------------------------------------

#define MFMAB(CB4, ACC) { \
    _Pragma("unroll") \
    for (int ks = 0; ks < 8; ++ks) { \
        int fsp = (CB4) * 8 + ks + 3; if (fsp > 511) fsp = 511; \
        const char* pa = ebb + ((fsp >> 3) * 32768 + (fsp & 7) * 1024); \
        b[(ks + 3) & 3][0] = *(const s8v*)(pa); \
        b[(ks + 3) & 3][1] = *(const s8v*)(pa + 8192); \
        b[(ks + 3) & 3][2] = *(const s8v*)(pa + 16384); \
        b[(ks + 3) & 3][3] = *(const s8v*)(pa + 24576); \
        _Pragma("unroll") \
        for (int fi = 0; fi < 2; ++fi) \
            _Pragma("unroll") \
            for (int fj = 0; fj < 4; ++fj) \
                ACC[fi][fj] = __builtin_amdgcn_mfma_f32_16x16x32_bf16( \
                    a[fi][ks], b[ks & 3][fj], \
                    ks ? ACC[fi][fj] : (f32x4){0.f, 0.f, 0.f, 0.f}, 0, 0, 0); \
    } }

#define EPI(CB4, ACC) { \
    int cbase = (CB4) * 64; \
    float eq0 = esq[cbase + lr], eq1 = esq[cbase + 16 + lr]; \
    float eq2 = esq[cbase + 32 + lr], eq3 = esq[cbase + 48 + lr]; \
    _Pragma("unroll") \
    for (int fi = 0; fi < 2; ++fi) { \
        _Pragma("unroll") \
        for (int rg = 0; rg < 4; ++rg) { \
            float xq = xr[fi][rg]; \
            float d0 = fmaxf(xq + eq0 - 2.f * ACC[fi][0][rg], 0.f); \
            float d1 = fmaxf(xq + eq1 - 2.f * ACC[fi][1][rg], 0.f); \
            float d2 = fmaxf(xq + eq2 - 2.f * ACC[fi][2][rg], 0.f); \
            float d3 = fmaxf(xq + eq3 - 2.f * ACC[fi][3][rg], 0.f); \
            size_t rbase = (size_t)(wg * 32 + fi * 16 + g * 4 + rg) * KCB + cbase; \
            outd[rbase + lr]      = d0; \
            outd[rbase + 16 + lr] = d1; \
            outd[rbase + 32 + lr] = d2; \
            outd[rbase + 48 + lr] = d3; \
            float m = fminf(fminf(d0, d1), fminf(d2, d3)); \
            m = fminf(m, __shfl_xor(m, 1)); m = fminf(m, __shfl_xor(m, 2)); \
            m = fminf(m, __shfl_xor(m, 4)); m = fminf(m, __shfl_xor(m, 8)); \
            float nm = fminf(runmin[fi][rg], m); runmin[fi][rg] = nm; \
            float thr = nm + MARGIN; \
            int rloc = fi * 16 + g * 4 + rg; \
            _Pragma("unroll") \
            for (int fj = 0; fj < 4; ++fj) { \
                float dv = (fj == 0) ? d0 : (fj == 1) ? d1 : (fj == 2) ? d2 : d3; \
                bool hit = dv <= thr; \
                unsigned long long mk = __ballot(hit); \
                if (mk) { \
                    unsigned m16 = (unsigned)(mk >> (g * 16)) & 0xffffu; \
                    int pos = cnt[fi][rg] + __popc(m16 & ((1u << lr) - 1u)); \
                    if (hit && pos < CAP) cand[widx][rloc][pos] = cbase + fj * 16 + lr; \
                    cnt[fi][rg] += __popc(m16); \
                } \
            } \
        } \
    } }

__global__ __launch_bounds__(256, 1)
void vq_main(const float* __restrict__ x, const float* __restrict__ e,
             const unsigned short* __restrict__ eb, const unsigned short* __restrict__ xb,
             const float* __restrict__ esq, const float* __restrict__ xsq,
             float* __restrict__ outq, float* __restrict__ outi, float* __restrict__ outd)
{
    __shared__ int cand[4][32][CAP];
    __shared__ int cntL[4][32];

    const int tid = threadIdx.x;
    const int widx = tid >> 6;
    const int l = tid & 63;
    const int lr = l & 15;
    const int g = l >> 4;
    const int wg = blockIdx.x * 4 + widx;     // 0..1023, owns rows wg*32..+31

    // ---- A fragments: 32 rows x 256 d in 64 VGPRs ----
    const char* xbb = (const char*)xb;
    s8v a[2][8];
    #pragma unroll
    for (int fi = 0; fi < 2; ++fi)
        #pragma unroll
        for (int ks = 0; ks < 8; ++ks)
            a[fi][ks] = *(const s8v*)(xbb +
                ((((size_t)(wg * 2 + fi) * 8 + ks) * 64 + l) << 4));

    float xr[2][4];
    #pragma unroll
    for (int fi = 0; fi < 2; ++fi)
        #pragma unroll
        for (int rg = 0; rg < 4; ++rg)
            xr[fi][rg] = xsq[wg * 32 + fi * 16 + g * 4 + rg];

    float runmin[2][4];
    int cnt[2][4];
    #pragma unroll
    for (int fi = 0; fi < 2; ++fi)
        #pragma unroll
        for (int rg = 0; rg < 4; ++rg) { runmin[fi][rg] = 1e30f; cnt[fi][rg] = 0; }

    f32x4 accA[2][4], accB[2][4];
    s8v b[4][4];
    const char* ebb = (const char*)eb + (l << 4);

    // preload fs = 0,1,2 into slots 0,1,2
    #pragma unroll
    for (int fs = 0; fs < 3; ++fs) {
        const char* pa = ebb + fs * 1024;
        b[fs][0] = *(const s8v*)(pa);
        b[fs][1] = *(const s8v*)(pa + 8192);
        b[fs][2] = *(const s8v*)(pa + 16384);
        b[fs][3] = *(const s8v*)(pa + 24576);
    }

    MFMAB(0, accA);
    #pragma unroll 1
    for (int cb2 = 0; cb2 < 31; ++cb2) {
        MFMAB(2 * cb2 + 1, accB);
        EPI(2 * cb2, accA);
        MFMAB(2 * cb2 + 2, accA);
        EPI(2 * cb2 + 1, accB);
    }
    MFMAB(63, accB);
    EPI(62, accA);
    EPI(63, accB);

    // ---- publish counts; refinement over candidates (exact fp64) ----
    if (lr == 0) {
        #pragma unroll
        for (int fi = 0; fi < 2; ++fi)
            #pragma unroll
            for (int rg = 0; rg < 4; ++rg)
                cntL[widx][fi * 16 + g * 4 + rg] = cnt[fi][rg] < CAP ? cnt[fi][rg] : CAP;
    }
    __syncthreads();

    const float4* xf4 = (const float4*)x;
    const float4* ef4 = (const float4*)e;
    float4* qf4 = (float4*)outq;
    for (int rw = 0; rw < 32; ++rw) {
        int grow = wg * 32 + rw;
        int nc = cntL[widx][rw];
        float4 xv = xf4[(size_t)grow * 64 + l];
        double best = 1e300;
        int bestj = 0;
        for (int c = 0; c < nc; ++c) {
            int j = cand[widx][rw][c];
            float4 ev = ef4[(size_t)j * 64 + l];
            double dx = (double)xv.x - (double)ev.x; double s = dx * dx;
            double dy = (double)xv.y - (double)ev.y; s += dy * dy;
            double dz = (double)xv.z - (double)ev.z; s += dz * dz;
            double dw = (double)xv.w - (double)ev.w; s += dw * dw;
            #pragma unroll
            for (int m = 32; m >= 1; m >>= 1) s += __shfl_xor(s, m);
            if (s < best || (s == best && j < bestj)) { best = s; bestj = j; }
        }
        if (l == 0) outi[grow] = (float)bestj;
        float4 q = ef4[(size_t)bestj * 64 + l];
        qf4[(size_t)grow * 64 + l] = q;
    }
}

extern "C" void kernel_launch(void* const* d_in, const int* in_sizes, int n_in,
                              void* d_out, int out_size, void* d_ws, size_t ws_size,
                              hipStream_t stream) {
    const float* x = (const float*)d_in[0];      // [32768, 256] f32
    const float* e = (const float*)d_in[1];      // [1, 4096, 256] f32
    char* ws = (char*)d_ws;
    unsigned short* eb  = (unsigned short*)ws;                               // 2 MB
    unsigned short* xb  = (unsigned short*)(ws + (size_t)2 * 1024 * 1024);   // 16 MB
    float* esq = (float*)(ws + (size_t)18 * 1024 * 1024);                    // 16 KB
    float* xsq = esq + KCB;                                                  // 128 KB

    float* outq = (float*)d_out;
    float* outi = outq + (size_t)NTOK * DIM;
    float* outd = outi + NTOK;

    prep<<<dim3(NTOK + KCB), dim3(64), 0, stream>>>(x, e, eb, xb, esq, xsq);
    vq_main<<<dim3(256), dim3(256), 0, stream>>>(x, e, eb, xb, esq, xsq,
                                                 outq, outi, outd);
}

// Round 4
// 730.479 us; speedup vs baseline: 1.3505x; 1.1992x over previous
//
#include <hip/hip_runtime.h>

#define NTOK 32768
#define DIM  256
#define KCB  4096
#define MARGIN 4.0f
#define CAP  24

typedef __attribute__((ext_vector_type(8))) short s8v;   // 8 bf16
typedef __attribute__((ext_vector_type(4))) float f32x4;

__device__ __forceinline__ unsigned short f2bf(float f) {
    union { float f; unsigned u; } v; v.f = f;
    unsigned r = v.u + 0x7FFFu + ((v.u >> 16) & 1u);
    return (unsigned short)(r >> 16);
}

// ---------------------------------------------------------------------------
// prep: fragment-order bf16 copies of e and x, plus exact fp32 sq-norms.
// Element (row, d): rb=row>>4, lr=row&15, ks=d>>5, g=(d>>3)&3, m=d&7
//   frag elem index = rb*4096 + ks*512 + (g*16+lr)*8 + m
// ---------------------------------------------------------------------------
__global__ __launch_bounds__(64)
void prep(const float* __restrict__ x, const float* __restrict__ e,
          unsigned short* __restrict__ eb, unsigned short* __restrict__ xb,
          float* __restrict__ esq, float* __restrict__ xsq)
{
    int j = blockIdx.x;
    int l = threadIdx.x;
    const float4* src; unsigned short* dstb; float* dsts; int row;
    if (j < KCB) { src = (const float4*)e; dstb = eb; dsts = esq; row = j; }
    else         { src = (const float4*)x; dstb = xb; dsts = xsq; row = j - KCB; }

    float4 v = src[(size_t)row * 64 + l];
    float s = v.x*v.x + v.y*v.y + v.z*v.z + v.w*v.w;
    #pragma unroll
    for (int m = 32; m >= 1; m >>= 1) s += __shfl_xor(s, m);
    if (l == 0) dsts[row] = s;

    int rb = row >> 4, lr = row & 15;
    int ks = l >> 3, g = (l >> 1) & 3;
    unsigned lo = (unsigned)f2bf(v.x) | ((unsigned)f2bf(v.y) << 16);
    unsigned hi = (unsigned)f2bf(v.z) | ((unsigned)f2bf(v.w) << 16);
    uint2 p; p.x = lo; p.y = hi;
    size_t eidx = (size_t)rb * 4096 + ks * 512 + (g * 16 + lr) * 8 + (l & 1) * 4;
    *(uint2*)(dstb + eidx) = p;
}

// ---------------------------------------------------------------------------
// main: 2048 waves, each owns 16 rows x full K. No barriers in hot loop.
// A (16x256) in 32 VGPRs; B streamed from L2 (4-slot ring, 3 k-steps ahead);
// nontemporal dist stores protect L2 residency of eb; double-buffered acc.
// ---------------------------------------------------------------------------

#define MFMAB(CB4, ACC) { \
    _Pragma("unroll") \
    for (int ks = 0; ks < 8; ++ks) { \
        int fsp = (CB4) * 8 + ks + 3; if (fsp > 511) fsp = 511; \
        const char* pa = ebb + ((fsp >> 3) * 32768 + (fsp & 7) * 1024); \
        b[(ks + 3) & 3][0] = *(const s8v*)(pa); \
        b[(ks + 3) & 3][1] = *(const s8v*)(pa + 8192); \
        b[(ks + 3) & 3][2] = *(const s8v*)(pa + 16384); \
        b[(ks + 3) & 3][3] = *(const s8v*)(pa + 24576); \
        _Pragma("unroll") \
        for (int fj = 0; fj < 4; ++fj) \
            ACC[fj] = __builtin_amdgcn_mfma_f32_16x16x32_bf16( \
                a[ks], b[ks & 3][fj], \
                ks ? ACC[fj] : (f32x4){0.f, 0.f, 0.f, 0.f}, 0, 0, 0); \
    } }

#define EPI(CB4, ACC) { \
    int cbase = (CB4) * 64; \
    float eq0 = esqL[cbase + lr], eq1 = esqL[cbase + 16 + lr]; \
    float eq2 = esqL[cbase + 32 + lr], eq3 = esqL[cbase + 48 + lr]; \
    _Pragma("unroll") \
    for (int rg = 0; rg < 4; ++rg) { \
        float xq = xr[rg]; \
        float d0 = fmaxf(xq + eq0 - 2.f * ACC[0][rg], 0.f); \
        float d1 = fmaxf(xq + eq1 - 2.f * ACC[1][rg], 0.f); \
        float d2 = fmaxf(xq + eq2 - 2.f * ACC[2][rg], 0.f); \
        float d3 = fmaxf(xq + eq3 - 2.f * ACC[3][rg], 0.f); \
        size_t rbase = (size_t)(wg * 16 + g * 4 + rg) * KCB + cbase; \
        __builtin_nontemporal_store(d0, &outd[rbase + lr]); \
        __builtin_nontemporal_store(d1, &outd[rbase + 16 + lr]); \
        __builtin_nontemporal_store(d2, &outd[rbase + 32 + lr]); \
        __builtin_nontemporal_store(d3, &outd[rbase + 48 + lr]); \
        float m = fminf(fminf(d0, d1), fminf(d2, d3)); \
        m = fminf(m, __shfl_xor(m, 1)); m = fminf(m, __shfl_xor(m, 2)); \
        m = fminf(m, __shfl_xor(m, 4)); m = fminf(m, __shfl_xor(m, 8)); \
        float nm = fminf(runmin[rg], m); runmin[rg] = nm; \
        float thr = nm + MARGIN; \
        int rloc = g * 4 + rg; \
        _Pragma("unroll") \
        for (int fj = 0; fj < 4; ++fj) { \
            float dv = (fj == 0) ? d0 : (fj == 1) ? d1 : (fj == 2) ? d2 : d3; \
            bool hit = dv <= thr; \
            unsigned long long mk = __ballot(hit); \
            if (mk) { \
                unsigned m16 = (unsigned)(mk >> (g * 16)) & 0xffffu; \
                int pos = cnt[rg] + __popc(m16 & ((1u << lr) - 1u)); \
                if (hit && pos < CAP) cand[widx][rloc][pos] = cbase + fj * 16 + lr; \
                cnt[rg] += __popc(m16); \
            } \
        } \
    } }

__global__ __launch_bounds__(256, 2)
void vq_main(const float* __restrict__ x, const float* __restrict__ e,
             const unsigned short* __restrict__ eb, const unsigned short* __restrict__ xb,
             const float* __restrict__ esq, const float* __restrict__ xsq,
             float* __restrict__ outq, float* __restrict__ outi, float* __restrict__ outd)
{
    __shared__ float esqL[KCB];            // 16 KB
    __shared__ int cand[4][16][CAP];       // 6 KB
    __shared__ int cntL[4][16];

    const int tid = threadIdx.x;
    const int widx = tid >> 6;
    const int l = tid & 63;
    const int lr = l & 15;
    const int g = l >> 4;
    const int wg = blockIdx.x * 4 + widx;     // 0..2047, owns rows wg*16..+15

    // stage esq into LDS (once per block)
    #pragma unroll
    for (int i = 0; i < KCB / 256; ++i)
        esqL[tid + i * 256] = esq[tid + i * 256];

    // ---- A fragments: 16 rows x 256 d in 32 VGPRs ----
    const char* xbb = (const char*)xb;
    s8v a[8];
    #pragma unroll
    for (int ks = 0; ks < 8; ++ks)
        a[ks] = *(const s8v*)(xbb + ((((size_t)wg * 8 + ks) * 64 + l) << 4));

    float xr[4];
    #pragma unroll
    for (int rg = 0; rg < 4; ++rg)
        xr[rg] = xsq[wg * 16 + g * 4 + rg];

    float runmin[4];
    int cnt[4];
    #pragma unroll
    for (int rg = 0; rg < 4; ++rg) { runmin[rg] = 1e30f; cnt[rg] = 0; }

    f32x4 accA[4], accB[4];
    s8v b[4][4];
    const char* ebb = (const char*)eb + (l << 4);

    // preload fs = 0,1,2 into ring slots 0,1,2
    #pragma unroll
    for (int fs = 0; fs < 3; ++fs) {
        const char* pa = ebb + fs * 1024;
        b[fs][0] = *(const s8v*)(pa);
        b[fs][1] = *(const s8v*)(pa + 8192);
        b[fs][2] = *(const s8v*)(pa + 16384);
        b[fs][3] = *(const s8v*)(pa + 24576);
    }

    __syncthreads();   // esqL ready (one-time)

    MFMAB(0, accA);
    #pragma unroll 1
    for (int cb2 = 0; cb2 < 31; ++cb2) {
        MFMAB(2 * cb2 + 1, accB);
        EPI(2 * cb2, accA);
        MFMAB(2 * cb2 + 2, accA);
        EPI(2 * cb2 + 1, accB);
    }
    MFMAB(63, accB);
    EPI(62, accA);
    EPI(63, accB);

    // ---- publish counts; refinement over candidates (exact fp64) ----
    if (lr == 0) {
        #pragma unroll
        for (int rg = 0; rg < 4; ++rg)
            cntL[widx][g * 4 + rg] = cnt[rg] < CAP ? cnt[rg] : CAP;
    }
    __syncthreads();

    const float4* xf4 = (const float4*)x;
    const float4* ef4 = (const float4*)e;
    f32x4* qf4 = (f32x4*)outq;
    for (int rw = 0; rw < 16; ++rw) {
        int grow = wg * 16 + rw;
        int nc = cntL[widx][rw];
        float4 xv = xf4[(size_t)grow * 64 + l];
        double best = 1e300;
        int bestj = 0;
        for (int c = 0; c < nc; ++c) {
            int j = cand[widx][rw][c];
            float4 ev = ef4[(size_t)j * 64 + l];
            double dx = (double)xv.x - (double)ev.x; double s = dx * dx;
            double dy = (double)xv.y - (double)ev.y; s += dy * dy;
            double dz = (double)xv.z - (double)ev.z; s += dz * dz;
            double dw = (double)xv.w - (double)ev.w; s += dw * dw;
            #pragma unroll
            for (int m = 32; m >= 1; m >>= 1) s += __shfl_xor(s, m);
            if (s < best || (s == best && j < bestj)) { best = s; bestj = j; }
        }
        if (l == 0) __builtin_nontemporal_store((float)bestj, &outi[grow]);
        float4 q = ef4[(size_t)bestj * 64 + l];
        f32x4 qv = {q.x, q.y, q.z, q.w};
        __builtin_nontemporal_store(qv, &qf4[(size_t)grow * 64 + l]);
    }
}

extern "C" void kernel_launch(void* const* d_in, const int* in_sizes, int n_in,
                              void* d_out, int out_size, void* d_ws, size_t ws_size,
                              hipStream_t stream) {
    const float* x = (const float*)d_in[0];      // [32768, 256] f32
    const float* e = (const float*)d_in[1];      // [1, 4096, 256] f32
    char* ws = (char*)d_ws;
    unsigned short* eb  = (unsigned short*)ws;                               // 2 MB
    unsigned short* xb  = (unsigned short*)(ws + (size_t)2 * 1024 * 1024);   // 16 MB
    float* esq = (float*)(ws + (size_t)18 * 1024 * 1024);                    // 16 KB
    float* xsq = esq + KCB;                                                  // 128 KB

    float* outq = (float*)d_out;
    float* outi = outq + (size_t)NTOK * DIM;
    float* outd = outi + NTOK;

    prep<<<dim3(NTOK + KCB), dim3(64), 0, stream>>>(x, e, eb, xb, esq, xsq);
    vq_main<<<dim3(512), dim3(256), 0, stream>>>(x, e, eb, xb, esq, xsq,
                                                 outq, outi, outd);
}